// Round 4
// baseline (2156.183 us; speedup 1.0000x reference)
//
#include <hip/hip_runtime.h>
#include <math.h>

// LSTMLightweight on MI355X (R4 = R3 gate-split + explicit ordering).
//   x[B,T,1] -> linear_in(1->16)+ReLU -> LSTM0(16) -> LSTM1(16) -> fc(16->8)+ReLU -> fc(8->1)
// 32 threads per element, 2 elements per 64-thread (1-wave) block, grid=B/2=4096
// waves -> 4 waves/SIMD. Thread (j, half): half0 owns gate rows {i:j, f:16+j} +
// cell state; half1 owns {g:32+j, o:48+j} + the h_j output. Gates combine via
// 2 shfl_xor(16) per layer (verified numerically vs reference).
// R4 vs R3: h-vector exchange is double-buffered on step parity and fenced with
// __syncthreads() (R3's barrier-free exchange failed at 0.137 absmax — ordering
// violation). launch_bounds(64,4) pins the VGPR budget at 128 = grid-limited
// occupancy, so the allocator needn't spill (~120 honest pressure).

#define EPW 2
#define TCHUNK 256
#define L2E 1.4426950408889634f

typedef float v2f __attribute__((ext_vector_type(2)));

__device__ __forceinline__ float sigm(float v) {
    return __builtin_amdgcn_rcpf(1.0f + __builtin_amdgcn_exp2f(-L2E * v));
}
__device__ __forceinline__ float tanh_(float v) {
    // tanh(v) = 1 - 2/(exp(2v)+1); saturates correctly at +-inf
    return 1.0f - 2.0f * __builtin_amdgcn_rcpf(1.0f + __builtin_amdgcn_exp2f((2.0f * L2E) * v));
}

// Finish a layer. aA/aB: packed partial sums for this thread's two gate rows.
// half0 (kA=-L2E,c1A=0,c2A=1): actA=sigm(i), actB=sigm(f), owns cc.
// half1 (kA=2L2E,c1A=1,c2A=-2): actA=tanh(g), actB=sigm(o); returns h_j=o*tanh(c).
__device__ __forceinline__ float lstm_finish(v2f aA, v2f aB, float kA, float c1A,
                                             float c2A, float& cc) {
    const float hA = aA[0] + aA[1];
    const float hB = aB[0] + aB[1];
    const float actA =
        fmaf(c2A, __builtin_amdgcn_rcpf(1.0f + __builtin_amdgcn_exp2f(kA * hA)), c1A);
    const float actB = sigm(hB);
    const float xg = __shfl_xor(actA, 16, 64);  // half0 <- tanh(g); half1 <- sigm(i)
    cc = fmaf(actB, cc, actA * xg);             // half0: c = f*c + i*g (half1: bounded junk)
    const float t = tanh_(cc);
    const float tx = __shfl_xor(t, 16, 64);     // half1 <- tanh(c)
    return actB * tx;                           // half1: h_j = o * tanh(c)
}

// packed dot with register-resident weights W[2][8] (v2f)
#define DOTR(AA, AB, W, HP)                                           \
    _Pragma("unroll")                                                 \
    for (int c = 0; c < 4; ++c) {                                     \
        v2f hlo = {HP[c].x, HP[c].y};                                 \
        v2f hhi = {HP[c].z, HP[c].w};                                 \
        AA = __builtin_elementwise_fma(W[0][2 * c], hlo, AA);         \
        AA = __builtin_elementwise_fma(W[0][2 * c + 1], hhi, AA);     \
        AB = __builtin_elementwise_fma(W[1][2 * c], hlo, AB);         \
        AB = __builtin_elementwise_fma(W[1][2 * c + 1], hhi, AB);     \
    }

// packed dot with two 16-float rows behind float4* (LDS or global)
#define DOTL(AA, AB, WROWA, WROWB, HP)                                \
    _Pragma("unroll")                                                 \
    for (int c = 0; c < 4; ++c) {                                     \
        float4 wa = ((const float4*)(WROWA))[c];                      \
        float4 wb = ((const float4*)(WROWB))[c];                      \
        v2f hlo = {HP[c].x, HP[c].y};                                 \
        v2f hhi = {HP[c].z, HP[c].w};                                 \
        AA = __builtin_elementwise_fma((v2f){wa.x, wa.y}, hlo, AA);   \
        AA = __builtin_elementwise_fma((v2f){wa.z, wa.w}, hhi, AA);   \
        AB = __builtin_elementwise_fma((v2f){wb.x, wb.y}, hlo, AB);   \
        AB = __builtin_elementwise_fma((v2f){wb.z, wb.w}, hhi, AB);   \
    }

__global__ __launch_bounds__(64, 4) void lstm_fused(
    const float* __restrict__ x,
    const float* __restrict__ w_in, const float* __restrict__ b_in,
    const float* __restrict__ w_ih0, const float* __restrict__ w_hh0,
    const float* __restrict__ b_ih0, const float* __restrict__ b_hh0,
    const float* __restrict__ w_ih1, const float* __restrict__ w_hh1,
    const float* __restrict__ b_ih1, const float* __restrict__ b_hh1,
    const float* __restrict__ fc_h_w, const float* __restrict__ fc_h_b,
    const float* __restrict__ fc_o_w, const float* __restrict__ fc_o_b,
    float* __restrict__ out, int B, int T)
{
    const int lane = threadIdx.x;       // 0..63
    const int e    = lane >> 5;         // element in block (0..1)
    const int sub  = lane & 31;
    const int j    = sub & 15;          // hidden unit
    const int half = sub >> 4;          // 0: gates {i,f}; 1: gates {g,o}
    const int elem  = blockIdx.x * EPW + e;
    const int elemc = elem < B ? elem : B - 1;
    const int rA = half * 32 + j;       // row of gate A (i or g)
    const int rB = rA + 16;             // row of gate B (f or o)

    __shared__ float  whh0s[64][20];    // padded: 80B rows, 16B-aligned
    __shared__ float  xs[EPW][TCHUNK];
    __shared__ float4 h0b[2][EPW][4];   // double-buffered h exchange
    __shared__ float4 h1b[2][EPW][4];
    __shared__ float  xib[EPW][16];     // fallback xi / head z exchange

    // ---- stage w_hh0 into LDS (lane r stages row r) ----
    {
        const int r = lane;
        const float4* src = (const float4*)(w_hh0 + r * 16);
        float4* dst = (float4*)&whh0s[r][0];
        #pragma unroll
        for (int c = 0; c < 4; ++c) dst[c] = src[c];
    }

    // ---- per-thread weights: w_ih1/w_hh1 rows rA,rB packed as v2f ----
    v2f wi1[2][8], wh1[2][8];
    float bb0[2], bb1[2], ap[2], an[2];
    #pragma unroll
    for (int g = 0; g < 2; ++g) {
        const int row = g ? rB : rA;
        const float4* pi = (const float4*)(w_ih1 + row * 16);
        const float4* ph = (const float4*)(w_hh1 + row * 16);
        #pragma unroll
        for (int c = 0; c < 4; ++c) {
            float4 ti = pi[c], th = ph[c];
            wi1[g][2 * c]     = (v2f){ti.x, ti.y};
            wi1[g][2 * c + 1] = (v2f){ti.z, ti.w};
            wh1[g][2 * c]     = (v2f){th.x, th.y};
            wh1[g][2 * c + 1] = (v2f){th.z, th.w};
        }
        bb0[g] = b_ih0[row] + b_hh0[row];
        bb1[g] = b_ih1[row] + b_hh1[row];
        ap[g] = 0.0f; an[g] = 0.0f;
    }

    // Fold linear_in(+ReLU) through w_ih0 (valid when b_in == 0):
    //   x>0: contribution = x*Ap ; x<=0: x*An
    bool bzero = true;
    #pragma unroll
    for (int k = 0; k < 16; ++k) {
        const float wk = w_in[k];
        if (b_in[k] != 0.0f) bzero = false;
        const float wp = fmaxf(wk, 0.0f), wn = fminf(wk, 0.0f);
        #pragma unroll
        for (int g = 0; g < 2; ++g) {
            const float wg = w_ih0[(g ? rB : rA) * 16 + k];
            ap[g] = fmaf(wg, wp, ap[g]);
            an[g] = fmaf(wg, wn, an[g]);
        }
    }

    // activation constants: A-gate is sigm on half0, tanh on half1
    const float kA  = half ? (2.0f * L2E) : (-L2E);
    const float c1A = half ? 1.0f : 0.0f;
    const float c2A = half ? -2.0f : 1.0f;

    // ---- zero state (read-buffer 0) ----
    if (half) {
        ((float*)&h0b[0][e][0])[j] = 0.0f;
        ((float*)&h1b[0][e][0])[j] = 0.0f;
    }
    float c0 = 0.0f, c1 = 0.0f;
    int p = 0;                          // read-buffer parity

    const float* xrow = x + (size_t)elemc * T;
    const float* wlA = &whh0s[rA][0];
    const float* wlB = &whh0s[rB][0];

    for (int tb = 0; tb < T; tb += TCHUNK) {
        const int tc = (T - tb) < TCHUNK ? (T - tb) : TCHUNK;
        __syncthreads();
        if (tc == TCHUNK && (T & 3) == 0) {
            for (int q = sub * 4; q < tc; q += 128)
                *(float4*)&xs[e][q] = *(const float4*)&xrow[tb + q];
        } else {
            for (int q = sub; q < tc; q += 32) xs[e][q] = xrow[tb + q];
        }
        __syncthreads();

        if (bzero) {
            for (int tt = 0; tt < tc; ++tt) {
                float4 hp[4];
                #pragma unroll
                for (int c = 0; c < 4; ++c) hp[c] = h0b[p][e][c];    // h0_{t-1}
                const float xv = xs[e][tt];
                const bool xp = xv > 0.0f;
                v2f aA = {fmaf(xv, xp ? ap[0] : an[0], bb0[0]), 0.0f};
                v2f aB = {fmaf(xv, xp ? ap[1] : an[1], bb0[1]), 0.0f};
                DOTL(aA, aB, wlA, wlB, hp);                          // + h0_{t-1}@w_hh0^T
                const float h0j = lstm_finish(aA, aB, kA, c1A, c2A, c0);
                if (half) ((float*)&h0b[p ^ 1][e][0])[j] = h0j;      // h0_t

                // h1-recurrent dot while the h0 write settles
                float4 hq[4];
                #pragma unroll
                for (int c = 0; c < 4; ++c) hq[c] = h1b[p][e][c];    // h1_{t-1}
                v2f bA = {bb1[0], 0.0f};
                v2f bB = {bb1[1], 0.0f};
                DOTR(bA, bB, wh1, hq);
                __syncthreads();                                     // h0_t visible
                float4 hn[4];
                #pragma unroll
                for (int c = 0; c < 4; ++c) hn[c] = h0b[p ^ 1][e][c];// h0_t
                DOTR(bA, bB, wi1, hn);
                const float h1j = lstm_finish(bA, bB, kA, c1A, c2A, c1);
                if (half) ((float*)&h1b[p ^ 1][e][0])[j] = h1j;      // h1_t
                __syncthreads();                                     // h1_t visible
                p ^= 1;
            }
        } else {
            // general path (b_in != 0): xi built cooperatively; w_ih0 read from
            // global (L2-cached). Never taken in this benchmark; correctness only.
            const float4* giA = (const float4*)(w_ih0 + rA * 16);
            const float4* giB = (const float4*)(w_ih0 + rB * 16);
            for (int tt = 0; tt < tc; ++tt) {
                const float xv = xs[e][tt];
                if (half == 0) xib[e][j] = fmaxf(fmaf(xv, w_in[j], b_in[j]), 0.0f);
                __syncthreads();
                float4 xi4[4];
                #pragma unroll
                for (int c = 0; c < 4; ++c) xi4[c] = *(const float4*)&xib[e][4 * c];
                v2f aA = {bb0[0], 0.0f};
                v2f aB = {bb0[1], 0.0f};
                DOTL(aA, aB, giA, giB, xi4);                         // xi @ w_ih0^T
                float4 hp[4];
                #pragma unroll
                for (int c = 0; c < 4; ++c) hp[c] = h0b[p][e][c];
                DOTL(aA, aB, wlA, wlB, hp);
                const float h0j = lstm_finish(aA, aB, kA, c1A, c2A, c0);
                if (half) ((float*)&h0b[p ^ 1][e][0])[j] = h0j;

                float4 hq[4];
                #pragma unroll
                for (int c = 0; c < 4; ++c) hq[c] = h1b[p][e][c];
                v2f bA = {bb1[0], 0.0f};
                v2f bB = {bb1[1], 0.0f};
                DOTR(bA, bB, wh1, hq);
                __syncthreads();
                float4 hn[4];
                #pragma unroll
                for (int c = 0; c < 4; ++c) hn[c] = h0b[p ^ 1][e][c];
                DOTR(bA, bB, wi1, hn);
                const float h1j = lstm_finish(bA, bB, kA, c1A, c2A, c1);
                if (half) ((float*)&h1b[p ^ 1][e][0])[j] = h1j;
                __syncthreads();
                p ^= 1;
            }
        }
    }

    // ---- head: fc_h (16->8) + ReLU, fc_o (8->1) ----
    if (half == 0 && j < 8) {
        float acc = fc_h_b[j];
        #pragma unroll
        for (int c = 0; c < 4; ++c) {
            float4 hv = h1b[p][e][c];
            acc = fmaf(fc_h_w[j * 16 + 4 * c + 0], hv.x, acc);
            acc = fmaf(fc_h_w[j * 16 + 4 * c + 1], hv.y, acc);
            acc = fmaf(fc_h_w[j * 16 + 4 * c + 2], hv.z, acc);
            acc = fmaf(fc_h_w[j * 16 + 4 * c + 3], hv.w, acc);
        }
        xib[e][j] = fmaxf(acc, 0.0f);
    }
    __syncthreads();
    if (sub == 0 && elem < B) {
        float acc = fc_o_b[0];
        #pragma unroll
        for (int r = 0; r < 8; ++r) acc = fmaf(fc_o_w[r], xib[e][r], acc);
        out[elem] = acc;
    }
}

extern "C" void kernel_launch(void* const* d_in, const int* in_sizes, int n_in,
                              void* d_out, int out_size, void* d_ws, size_t ws_size,
                              hipStream_t stream) {
    const float* x      = (const float*)d_in[0];
    const float* w_in   = (const float*)d_in[1];
    const float* b_in   = (const float*)d_in[2];
    const float* w_ih0  = (const float*)d_in[3];
    const float* w_hh0  = (const float*)d_in[4];
    const float* b_ih0  = (const float*)d_in[5];
    const float* b_hh0  = (const float*)d_in[6];
    const float* w_ih1  = (const float*)d_in[7];
    const float* w_hh1  = (const float*)d_in[8];
    const float* b_ih1  = (const float*)d_in[9];
    const float* b_hh1  = (const float*)d_in[10];
    const float* fc_h_w = (const float*)d_in[11];
    const float* fc_h_b = (const float*)d_in[12];
    const float* fc_o_w = (const float*)d_in[13];
    const float* fc_o_b = (const float*)d_in[14];

    const int B = out_size;                 // x is [B,T,1]
    const int T = in_sizes[0] / (B > 0 ? B : 1);
    const int grid = (B + EPW - 1) / EPW;

    hipLaunchKernelGGL(lstm_fused, dim3(grid), dim3(64), 0, stream,
                       x, w_in, b_in, w_ih0, w_hh0, b_ih0, b_hh0,
                       w_ih1, w_hh1, b_ih1, b_hh1, fc_h_w, fc_h_b,
                       fc_o_w, fc_o_b, (float*)d_out, B, T);
}

// Round 5
// 353.265 us; speedup vs baseline: 6.1036x; 6.1036x over previous
//
#include <hip/hip_runtime.h>
#include <math.h>

// LSTMLightweight on MI355X (R5 = R4 with the register cap fixed).
//   x[B,T,1] -> linear_in(1->16)+ReLU -> LSTM0(16) -> LSTM1(16) -> fc(16->8)+ReLU -> fc(8->1)
// 32 threads per element, 2 elements per 64-thread (1-wave) block, grid=B/2=4096
// waves -> 4 waves/SIMD. Thread (j, half): half0 owns gate rows {i:j, f:16+j} +
// cell state; half1 owns {g:32+j, o:48+j} + the h_j output. Gates combine via
// 2 shfl_xor(16) per layer. h exchange double-buffered + __syncthreads fenced.
// R4 lesson: __launch_bounds__(64,4) = min 4 waves/EU = 64-VGPR cap -> wholesale
// spill of the ~110-reg working set, 4.2 GB scratch re-reads, 2156 us.
// R5: __launch_bounds__(64,2) -> 128-VGPR cap >= honest pressure, no spill;
// grid still gives 4 waves/SIMD at 128 VGPR.

#define EPW 2
#define TCHUNK 256
#define L2E 1.4426950408889634f

typedef float v2f __attribute__((ext_vector_type(2)));

__device__ __forceinline__ float sigm(float v) {
    return __builtin_amdgcn_rcpf(1.0f + __builtin_amdgcn_exp2f(-L2E * v));
}
__device__ __forceinline__ float tanh_(float v) {
    // tanh(v) = 1 - 2/(exp(2v)+1); saturates correctly at +-inf
    return 1.0f - 2.0f * __builtin_amdgcn_rcpf(1.0f + __builtin_amdgcn_exp2f((2.0f * L2E) * v));
}

// Finish a layer. aA/aB: packed partial sums for this thread's two gate rows.
// half0 (kA=-L2E,c1A=0,c2A=1): actA=sigm(i), actB=sigm(f), owns cc.
// half1 (kA=2L2E,c1A=1,c2A=-2): actA=tanh(g), actB=sigm(o); returns h_j=o*tanh(c).
__device__ __forceinline__ float lstm_finish(v2f aA, v2f aB, float kA, float c1A,
                                             float c2A, float& cc) {
    const float hA = aA[0] + aA[1];
    const float hB = aB[0] + aB[1];
    const float actA =
        fmaf(c2A, __builtin_amdgcn_rcpf(1.0f + __builtin_amdgcn_exp2f(kA * hA)), c1A);
    const float actB = sigm(hB);
    const float xg = __shfl_xor(actA, 16, 64);  // half0 <- tanh(g); half1 <- sigm(i)
    cc = fmaf(actB, cc, actA * xg);             // half0: c = f*c + i*g (half1: bounded junk)
    const float t = tanh_(cc);
    const float tx = __shfl_xor(t, 16, 64);     // half1 <- tanh(c)
    return actB * tx;                           // half1: h_j = o * tanh(c)
}

// packed dot with register-resident weights W[2][8] (v2f)
#define DOTR(AA, AB, W, HP)                                           \
    _Pragma("unroll")                                                 \
    for (int c = 0; c < 4; ++c) {                                     \
        v2f hlo = {HP[c].x, HP[c].y};                                 \
        v2f hhi = {HP[c].z, HP[c].w};                                 \
        AA = __builtin_elementwise_fma(W[0][2 * c], hlo, AA);         \
        AA = __builtin_elementwise_fma(W[0][2 * c + 1], hhi, AA);     \
        AB = __builtin_elementwise_fma(W[1][2 * c], hlo, AB);         \
        AB = __builtin_elementwise_fma(W[1][2 * c + 1], hhi, AB);     \
    }

// packed dot with two 16-float rows behind float4* (LDS or global)
#define DOTL(AA, AB, WROWA, WROWB, HP)                                \
    _Pragma("unroll")                                                 \
    for (int c = 0; c < 4; ++c) {                                     \
        float4 wa = ((const float4*)(WROWA))[c];                      \
        float4 wb = ((const float4*)(WROWB))[c];                      \
        v2f hlo = {HP[c].x, HP[c].y};                                 \
        v2f hhi = {HP[c].z, HP[c].w};                                 \
        AA = __builtin_elementwise_fma((v2f){wa.x, wa.y}, hlo, AA);   \
        AA = __builtin_elementwise_fma((v2f){wa.z, wa.w}, hhi, AA);   \
        AB = __builtin_elementwise_fma((v2f){wb.x, wb.y}, hlo, AB);   \
        AB = __builtin_elementwise_fma((v2f){wb.z, wb.w}, hhi, AB);   \
    }

__global__ __launch_bounds__(64, 2) void lstm_fused(
    const float* __restrict__ x,
    const float* __restrict__ w_in, const float* __restrict__ b_in,
    const float* __restrict__ w_ih0, const float* __restrict__ w_hh0,
    const float* __restrict__ b_ih0, const float* __restrict__ b_hh0,
    const float* __restrict__ w_ih1, const float* __restrict__ w_hh1,
    const float* __restrict__ b_ih1, const float* __restrict__ b_hh1,
    const float* __restrict__ fc_h_w, const float* __restrict__ fc_h_b,
    const float* __restrict__ fc_o_w, const float* __restrict__ fc_o_b,
    float* __restrict__ out, int B, int T)
{
    const int lane = threadIdx.x;       // 0..63
    const int e    = lane >> 5;         // element in block (0..1)
    const int sub  = lane & 31;
    const int j    = sub & 15;          // hidden unit
    const int half = sub >> 4;          // 0: gates {i,f}; 1: gates {g,o}
    const int elem  = blockIdx.x * EPW + e;
    const int elemc = elem < B ? elem : B - 1;
    const int rA = half * 32 + j;       // row of gate A (i or g)
    const int rB = rA + 16;             // row of gate B (f or o)

    __shared__ float  whh0s[64][20];    // padded: 80B rows, 16B-aligned
    __shared__ float  xs[EPW][TCHUNK];
    __shared__ float4 h0b[2][EPW][4];   // double-buffered h exchange
    __shared__ float4 h1b[2][EPW][4];
    __shared__ float  xib[EPW][16];     // fallback xi / head z exchange

    // ---- stage w_hh0 into LDS (lane r stages row r) ----
    {
        const int r = lane;
        const float4* src = (const float4*)(w_hh0 + r * 16);
        float4* dst = (float4*)&whh0s[r][0];
        #pragma unroll
        for (int c = 0; c < 4; ++c) dst[c] = src[c];
    }

    // ---- per-thread weights: w_ih1/w_hh1 rows rA,rB packed as v2f ----
    v2f wi1[2][8], wh1[2][8];
    float bb0[2], bb1[2], ap[2], an[2];
    #pragma unroll
    for (int g = 0; g < 2; ++g) {
        const int row = g ? rB : rA;
        const float4* pi = (const float4*)(w_ih1 + row * 16);
        const float4* ph = (const float4*)(w_hh1 + row * 16);
        #pragma unroll
        for (int c = 0; c < 4; ++c) {
            float4 ti = pi[c], th = ph[c];
            wi1[g][2 * c]     = (v2f){ti.x, ti.y};
            wi1[g][2 * c + 1] = (v2f){ti.z, ti.w};
            wh1[g][2 * c]     = (v2f){th.x, th.y};
            wh1[g][2 * c + 1] = (v2f){th.z, th.w};
        }
        bb0[g] = b_ih0[row] + b_hh0[row];
        bb1[g] = b_ih1[row] + b_hh1[row];
        ap[g] = 0.0f; an[g] = 0.0f;
    }

    // Fold linear_in(+ReLU) through w_ih0 (valid when b_in == 0):
    //   x>0: contribution = x*Ap ; x<=0: x*An
    bool bzero = true;
    #pragma unroll
    for (int k = 0; k < 16; ++k) {
        const float wk = w_in[k];
        if (b_in[k] != 0.0f) bzero = false;
        const float wp = fmaxf(wk, 0.0f), wn = fminf(wk, 0.0f);
        #pragma unroll
        for (int g = 0; g < 2; ++g) {
            const float wg = w_ih0[(g ? rB : rA) * 16 + k];
            ap[g] = fmaf(wg, wp, ap[g]);
            an[g] = fmaf(wg, wn, an[g]);
        }
    }

    // activation constants: A-gate is sigm on half0, tanh on half1
    const float kA  = half ? (2.0f * L2E) : (-L2E);
    const float c1A = half ? 1.0f : 0.0f;
    const float c2A = half ? -2.0f : 1.0f;

    // ---- zero state (read-buffer 0) ----
    if (half) {
        ((float*)&h0b[0][e][0])[j] = 0.0f;
        ((float*)&h1b[0][e][0])[j] = 0.0f;
    }
    float c0 = 0.0f, c1 = 0.0f;
    int p = 0;                          // read-buffer parity

    const float* xrow = x + (size_t)elemc * T;
    const float* wlA = &whh0s[rA][0];
    const float* wlB = &whh0s[rB][0];

    for (int tb = 0; tb < T; tb += TCHUNK) {
        const int tc = (T - tb) < TCHUNK ? (T - tb) : TCHUNK;
        __syncthreads();
        if (tc == TCHUNK && (T & 3) == 0) {
            for (int q = sub * 4; q < tc; q += 128)
                *(float4*)&xs[e][q] = *(const float4*)&xrow[tb + q];
        } else {
            for (int q = sub; q < tc; q += 32) xs[e][q] = xrow[tb + q];
        }
        __syncthreads();

        if (bzero) {
            for (int tt = 0; tt < tc; ++tt) {
                float4 hp[4];
                #pragma unroll
                for (int c = 0; c < 4; ++c) hp[c] = h0b[p][e][c];    // h0_{t-1}
                const float xv = xs[e][tt];
                const bool xp = xv > 0.0f;
                v2f aA = {fmaf(xv, xp ? ap[0] : an[0], bb0[0]), 0.0f};
                v2f aB = {fmaf(xv, xp ? ap[1] : an[1], bb0[1]), 0.0f};
                DOTL(aA, aB, wlA, wlB, hp);                          // + h0_{t-1}@w_hh0^T
                const float h0j = lstm_finish(aA, aB, kA, c1A, c2A, c0);
                if (half) ((float*)&h0b[p ^ 1][e][0])[j] = h0j;      // h0_t

                // h1-recurrent dot while the h0 write settles
                float4 hq[4];
                #pragma unroll
                for (int c = 0; c < 4; ++c) hq[c] = h1b[p][e][c];    // h1_{t-1}
                v2f bA = {bb1[0], 0.0f};
                v2f bB = {bb1[1], 0.0f};
                DOTR(bA, bB, wh1, hq);
                __syncthreads();                                     // h0_t visible
                float4 hn[4];
                #pragma unroll
                for (int c = 0; c < 4; ++c) hn[c] = h0b[p ^ 1][e][c];// h0_t
                DOTR(bA, bB, wi1, hn);
                const float h1j = lstm_finish(bA, bB, kA, c1A, c2A, c1);
                if (half) ((float*)&h1b[p ^ 1][e][0])[j] = h1j;      // h1_t
                __syncthreads();                                     // h1_t visible
                p ^= 1;
            }
        } else {
            // general path (b_in != 0): xi built cooperatively; w_ih0 read from
            // global (L2-cached). Never taken in this benchmark; correctness only.
            const float4* giA = (const float4*)(w_ih0 + rA * 16);
            const float4* giB = (const float4*)(w_ih0 + rB * 16);
            for (int tt = 0; tt < tc; ++tt) {
                const float xv = xs[e][tt];
                if (half == 0) xib[e][j] = fmaxf(fmaf(xv, w_in[j], b_in[j]), 0.0f);
                __syncthreads();
                float4 xi4[4];
                #pragma unroll
                for (int c = 0; c < 4; ++c) xi4[c] = *(const float4*)&xib[e][4 * c];
                v2f aA = {bb0[0], 0.0f};
                v2f aB = {bb0[1], 0.0f};
                DOTL(aA, aB, giA, giB, xi4);                         // xi @ w_ih0^T
                float4 hp[4];
                #pragma unroll
                for (int c = 0; c < 4; ++c) hp[c] = h0b[p][e][c];
                DOTL(aA, aB, wlA, wlB, hp);
                const float h0j = lstm_finish(aA, aB, kA, c1A, c2A, c0);
                if (half) ((float*)&h0b[p ^ 1][e][0])[j] = h0j;

                float4 hq[4];
                #pragma unroll
                for (int c = 0; c < 4; ++c) hq[c] = h1b[p][e][c];
                v2f bA = {bb1[0], 0.0f};
                v2f bB = {bb1[1], 0.0f};
                DOTR(bA, bB, wh1, hq);
                __syncthreads();
                float4 hn[4];
                #pragma unroll
                for (int c = 0; c < 4; ++c) hn[c] = h0b[p ^ 1][e][c];
                DOTR(bA, bB, wi1, hn);
                const float h1j = lstm_finish(bA, bB, kA, c1A, c2A, c1);
                if (half) ((float*)&h1b[p ^ 1][e][0])[j] = h1j;
                __syncthreads();
                p ^= 1;
            }
        }
    }

    // ---- head: fc_h (16->8) + ReLU, fc_o (8->1) ----
    if (half == 0 && j < 8) {
        float acc = fc_h_b[j];
        #pragma unroll
        for (int c = 0; c < 4; ++c) {
            float4 hv = h1b[p][e][c];
            acc = fmaf(fc_h_w[j * 16 + 4 * c + 0], hv.x, acc);
            acc = fmaf(fc_h_w[j * 16 + 4 * c + 1], hv.y, acc);
            acc = fmaf(fc_h_w[j * 16 + 4 * c + 2], hv.z, acc);
            acc = fmaf(fc_h_w[j * 16 + 4 * c + 3], hv.w, acc);
        }
        xib[e][j] = fmaxf(acc, 0.0f);
    }
    __syncthreads();
    if (sub == 0 && elem < B) {
        float acc = fc_o_b[0];
        #pragma unroll
        for (int r = 0; r < 8; ++r) acc = fmaf(fc_o_w[r], xib[e][r], acc);
        out[elem] = acc;
    }
}

extern "C" void kernel_launch(void* const* d_in, const int* in_sizes, int n_in,
                              void* d_out, int out_size, void* d_ws, size_t ws_size,
                              hipStream_t stream) {
    const float* x      = (const float*)d_in[0];
    const float* w_in   = (const float*)d_in[1];
    const float* b_in   = (const float*)d_in[2];
    const float* w_ih0  = (const float*)d_in[3];
    const float* w_hh0  = (const float*)d_in[4];
    const float* b_ih0  = (const float*)d_in[5];
    const float* b_hh0  = (const float*)d_in[6];
    const float* w_ih1  = (const float*)d_in[7];
    const float* w_hh1  = (const float*)d_in[8];
    const float* b_ih1  = (const float*)d_in[9];
    const float* b_hh1  = (const float*)d_in[10];
    const float* fc_h_w = (const float*)d_in[11];
    const float* fc_h_b = (const float*)d_in[12];
    const float* fc_o_w = (const float*)d_in[13];
    const float* fc_o_b = (const float*)d_in[14];

    const int B = out_size;                 // x is [B,T,1]
    const int T = in_sizes[0] / (B > 0 ? B : 1);
    const int grid = (B + EPW - 1) / EPW;

    hipLaunchKernelGGL(lstm_fused, dim3(grid), dim3(64), 0, stream,
                       x, w_in, b_in, w_ih0, w_hh0, b_ih0, b_hh0,
                       w_ih1, w_hh1, b_ih1, b_hh1, fc_h_w, fc_h_b,
                       fc_o_w, fc_o_b, (float*)d_out, B, T);
}